// Round 2
// baseline (432.531 us; speedup 1.0000x reference)
//
#include <hip/hip_runtime.h>

// x: (F=64, A=128, C=2, N=4096) fp32 -> rows = 16384 signals of length 4096.
// Each row: 1x3 conv -> 4094 outputs; weights by channel (row & 1).
// out flat: row * 4094 + j.
//
// Store-alignment trick: row*4094 mod 4 == 2*(row&1). Shifting each thread's
// output window by -2 elements on odd rows makes EVERY float4 store 16B-aligned
// on every row (dense, memset-like write stream). Loads are two aligned float4
// per thread (overlap between neighbors served by L1 broadcast).

#define N_IN 4096
#define N_OUT 4094
#define CPR 1024              // chunks per row
#define ROWS 16384

__global__ __launch_bounds__(256) void RTGRFID_51539607553079_kernel(
    const float* __restrict__ x,
    const float* __restrict__ w_rssi,  const float* __restrict__ b_rssi,
    const float* __restrict__ w_phase, const float* __restrict__ b_phase,
    float* __restrict__ out)
{
    const unsigned tid = blockIdx.x * blockDim.x + threadIdx.x;
    const int row = tid >> 10;
    const int c   = tid & (CPR - 1);
    const int odd = row & 1;

    // Block-uniform channel select (256 | 1024) -> no real divergence.
    const float w0 = odd ? w_phase[0] : w_rssi[0];
    const float w1 = odd ? w_phase[1] : w_rssi[1];
    const float w2 = odd ? w_phase[2] : w_rssi[2];
    const float b  = odd ? b_phase[0] : b_rssi[0];

    const float4* in4 = (const float4*)(x + (size_t)row * N_IN);

    // Thread's output window: [4c - 2*odd, 4c - 2*odd + 4).
    // Inputs needed: s[4c-2*odd .. 4c-2*odd+5] -> float4s P=in4[c-odd], Q=in4[c-odd+1].
    const int pi = c - odd;                 // -1 only when odd && c==0
    const int qi = pi + 1;                  // 1024 only when even && c==1023
    const float4 P = in4[pi < 0 ? 0 : pi];          // clamped value unused at edge
    const float4 Q = in4[qi > CPR - 1 ? CPR - 1 : qi];

    float t0, t1, t2, t3, t4, t5;
    if (odd) { t0 = P.z; t1 = P.w; t2 = Q.x; t3 = Q.y; t4 = Q.z; t5 = Q.w; }
    else     { t0 = P.x; t1 = P.y; t2 = P.z; t3 = P.w; t4 = Q.x; t5 = Q.y; }

    const float o0 = fmaf(w0, t0, fmaf(w1, t1, fmaf(w2, t2, b)));
    const float o1 = fmaf(w0, t1, fmaf(w1, t2, fmaf(w2, t3, b)));
    const float o2 = fmaf(w0, t2, fmaf(w1, t3, fmaf(w2, t4, b)));
    const float o3 = fmaf(w0, t3, fmaf(w1, t4, fmaf(w2, t5, b)));

    float* ob = out + (size_t)row * N_OUT + (c << 2) - 2 * odd;

    if (odd && c == 0) {
        // Valid outputs are j=0,1 (o2,o3); ob points 2 before row start.
        *(float2*)(ob + 2) = make_float2(o2, o3);           // 8B-aligned
    } else if (!odd && c == CPR - 1) {
        // Valid outputs are j=4092,4093 (o0,o1).
        *(float2*)ob = make_float2(o0, o1);                 // 16B-aligned
    } else {
        *(float4*)ob = make_float4(o0, o1, o2, o3);         // 16B-aligned always
    }
}

extern "C" void kernel_launch(void* const* d_in, const int* in_sizes, int n_in,
                              void* d_out, int out_size, void* d_ws, size_t ws_size,
                              hipStream_t stream) {
    const float* x       = (const float*)d_in[0];
    const float* w_rssi  = (const float*)d_in[1];
    const float* b_rssi  = (const float*)d_in[2];
    const float* w_phase = (const float*)d_in[3];
    const float* b_phase = (const float*)d_in[4];
    float* out = (float*)d_out;

    const unsigned total_threads = (unsigned)ROWS * CPR;    // 16,777,216
    const unsigned block = 256;
    const unsigned grid = total_threads / block;            // 65,536

    RTGRFID_51539607553079_kernel<<<grid, block, 0, stream>>>(
        x, w_rssi, b_rssi, w_phase, b_phase, out);
}